// Round 14
// baseline (323.057 us; speedup 1.0000x reference)
//
#include <hip/hip_runtime.h>
#include <hip/hip_bf16.h>
#include <math.h>

typedef __hip_bfloat16 bf16;
typedef __attribute__((ext_vector_type(8))) short short8;
typedef __attribute__((ext_vector_type(4))) float f32x4;

#define AS1 __attribute__((address_space(1)))
#define AS3 __attribute__((address_space(3)))

#define D_MODEL 1024
#define D_INNER 2048
#define N_HEADS 8
#define D_STATE 64
#define CHUNK 64
#define HEAD_DIM 256
#define NCHUNK 4
#define BATCH 32
#define SEQ 256
#define ROWS (BATCH*SEQ)          // 8192
#define PROJ_N 5128
#define PROJ_NPAD 5376            // 42 tiles of 128
#define O1 D_INNER                // 2048
#define O2 (2*D_INNER)            // 4096
#define O3 (O2 + N_HEADS*D_STATE) // 4608
#define O4 (O3 + N_HEADS*D_STATE) // 5120
#define EPSF 1.1920929e-07f

__device__ __forceinline__ float silu_f(float x){ return x / (1.0f + expf(-x)); }
__device__ __forceinline__ float b2f(bf16 v){ return __bfloat162float(v); }
__device__ __forceinline__ bf16  f2b(float v){ return __float2bfloat16(v); }
__device__ __forceinline__ short f2s(float v){ bf16 b = __float2bfloat16(v); union{bf16 b; short s;} u; u.b=b; return u.s; }
__device__ __forceinline__ float s2f(short v){ union{short s; bf16 b;} u; u.s=v; return __bfloat162float(u.b); }

__device__ __forceinline__ void gl16(const void* g, void* l){
    __builtin_amdgcn_global_load_lds((const AS1 void*)g, (AS3 void*)l, 16, 0, 0);
}

__device__ __forceinline__ float block_sum_256(float v){
    __shared__ float sm[4];
    #pragma unroll
    for (int o = 32; o > 0; o >>= 1) v += __shfl_down(v, o, 64);
    int lane = threadIdx.x & 63, w = threadIdx.x >> 6;
    if (lane == 0) sm[w] = v;
    __syncthreads();
    return sm[0] + sm[1] + sm[2] + sm[3];
}

// ---------------- RMSNorm (input) -> bf16 ----------------
__global__ __launch_bounds__(256) void k_rms_in(const float* __restrict__ x,
                                                const float* __restrict__ g,
                                                bf16* __restrict__ out){
    int row = blockIdx.x, t = threadIdx.x;
    const float4* xr = (const float4*)(x + (size_t)row * D_MODEL);
    float4 v = xr[t];
    float ss = v.x*v.x + v.y*v.y + v.z*v.z + v.w*v.w;
    ss = block_sum_256(ss);
    float sc = rsqrtf(ss * (1.0f/(float)D_MODEL) + EPSF);
    float4 gv = ((const float4*)g)[t];
    union { ushort4 u; bf16 b[4]; } o;
    o.b[0] = f2b(v.x*sc*gv.x); o.b[1] = f2b(v.y*sc*gv.y);
    o.b[2] = f2b(v.z*sc*gv.z); o.b[3] = f2b(v.w*sc*gv.w);
    ((ushort4*)(out + (size_t)row * D_MODEL))[t] = o.u;
}

// ---------------- both weight casts in one launch ----------------
// region 1: W_in [5128x1024] -> Wb1 [5376x1024] bf16 zero-padded
// region 2: W_out[1024x2048] * g_out[k] -> Wb2 bf16
#define N1 (PROJ_NPAD*D_MODEL)
__global__ __launch_bounds__(256) void k_cvt_both(const float* __restrict__ W_in,
                                                  const float* __restrict__ W_out,
                                                  const float* __restrict__ g_out,
                                                  bf16* __restrict__ Wb1,
                                                  bf16* __restrict__ Wb2){
    int i = (blockIdx.x * 256 + threadIdx.x) * 4;
    union { ushort4 u; bf16 b[4]; } o;
    if (i < N1){
        int n_in = PROJ_N*D_MODEL;
        if (i + 3 < n_in){
            float4 v = *(const float4*)(W_in + i);
            o.b[0]=f2b(v.x); o.b[1]=f2b(v.y); o.b[2]=f2b(v.z); o.b[3]=f2b(v.w);
        } else {
            #pragma unroll
            for (int j = 0; j < 4; j++) o.b[j] = f2b((i+j < n_in) ? W_in[i+j] : 0.f);
        }
        *(ushort4*)(Wb1 + i) = o.u;
    } else {
        int k2 = i - N1;
        if (k2 < D_MODEL*D_INNER){
            float4 v = *(const float4*)(W_out + k2);
            float4 gv = *(const float4*)(g_out + (k2 & (D_INNER-1)));
            o.b[0]=f2b(v.x*gv.x); o.b[1]=f2b(v.y*gv.y); o.b[2]=f2b(v.z*gv.z); o.b[3]=f2b(v.w*gv.w);
            *(ushort4*)(Wb2 + k2) = o.u;
        }
    }
}

// ================= NT GEMM, 256x128 tile, 8 waves / 512 thr, BK=32 =================
// LDS slot (srow,s8) holds global (srow*2 + ((s8^(srow&7))>>2), kgrp (s8^(srow&7))&3).

__device__ __forceinline__ short8 ld32(const short* base, int row, int g){
    int sr = row >> 1;
    int e8 = (((row & 1) << 2) | g) ^ (sr & 7);
    return *(const short8*)(base + sr*64 + e8*8);
}

__device__ __forceinline__ void stage_u(const bf16* __restrict__ Ag,
                                        const bf16* __restrict__ Bg,
                                        int K, size_t bm, size_t bn, int t,
                                        short* buf, int j){
    const int tid = threadIdx.x;         // 512 threads
    const int wid = tid >> 6;
    int cidx = j*512 + tid;              // 0..1535 slot index
    int srow = cidx >> 3, s8 = cidx & 7;
    int eff = s8 ^ (srow & 7);
    int grow = srow*2 + (eff >> 2);      // 0..383
    int gcol = t*32 + (eff & 3)*8;
    const bf16* src = (grow < 256)
        ? Ag + (bm + grow) * (size_t)K + gcol
        : Bg + (bn + grow - 256) * (size_t)K + gcol;
    gl16(src, buf + (size_t)(j*512 + wid*64)*8);   // wave-uniform base + lane*16B
}

#define MFMA_BF16(A_,B_,C_) __builtin_amdgcn_mfma_f32_16x16x32_bf16(A_,B_,C_,0,0,0)

// ---- ring-3 (72 KB), per-wave 64x64 — R9 proven (gemm1) ----
__device__ __forceinline__ void gemm_main(const bf16* __restrict__ Ag,
                                          const bf16* __restrict__ Bg,
                                          int K, size_t bm, size_t bn,
                                          short* lds, f32x4 (&acc)[4][4]){
    constexpr int TILE = 384*32;
    const int NT = K >> 5;
    const int lane = threadIdx.x & 63;
    const int wid = threadIdx.x >> 6;
    const int wm = wid >> 1, wn = wid & 1;
    const int fr = lane & 15, g = lane >> 4;

    #pragma unroll
    for (int j = 0; j < 3; j++) stage_u(Ag, Bg, K, bm, bn, 0, lds, j);
    #pragma unroll
    for (int j = 0; j < 3; j++) stage_u(Ag, Bg, K, bm, bn, 1, lds + TILE, j);
    asm volatile("s_waitcnt vmcnt(3)" ::: "memory");
    __builtin_amdgcn_sched_barrier(0);
    __builtin_amdgcn_s_barrier();
    __builtin_amdgcn_sched_barrier(0);

    int cur = 0;
    for (int t = 0; t < NT; t++){
        short* buf = lds + cur*TILE;
        int sg = cur + 2; if (sg >= 3) sg -= 3;
        short* stg = lds + sg*TILE;
        short8 a[4], b[4];
        #pragma unroll
        for (int m = 0; m < 4; m++) a[m] = ld32(buf, wm*64 + m*16 + fr, g);
        #pragma unroll
        for (int n = 0; n < 4; n++) b[n] = ld32(buf, 256 + wn*64 + n*16 + fr, g);
        if (t + 2 < NT){
            stage_u(Ag, Bg, K, bm, bn, t+2, stg, 0);
            stage_u(Ag, Bg, K, bm, bn, t+2, stg, 1);
            stage_u(Ag, Bg, K, bm, bn, t+2, stg, 2);
        }
        __builtin_amdgcn_s_setprio(1);
        #pragma unroll
        for (int m = 0; m < 4; m++)
            #pragma unroll
            for (int n = 0; n < 4; n++)
                acc[m][n] = MFMA_BF16(a[m], b[n], acc[m][n]);
        __builtin_amdgcn_s_setprio(0);
        __builtin_amdgcn_sched_barrier(0);
        if (t + 2 < NT)      asm volatile("s_waitcnt vmcnt(3)" ::: "memory");
        else if (t + 1 < NT) asm volatile("s_waitcnt vmcnt(0)" ::: "memory");
        __builtin_amdgcn_sched_barrier(0);
        __builtin_amdgcn_s_barrier();
        __builtin_amdgcn_sched_barrier(0);
        cur = cur + 1 == 3 ? 0 : cur + 1;
    }
}

// ---- ring-4 (96 KB), deeper prefetch for gemm2 (1 block/CU) ----
__device__ __forceinline__ void gemm_main_r4(const bf16* __restrict__ Ag,
                                             const bf16* __restrict__ Bg,
                                             int K, size_t bm, size_t bn,
                                             short* lds, f32x4 (&acc)[4][4]){
    constexpr int TILE = 384*32;
    const int NT = K >> 5;
    const int lane = threadIdx.x & 63;
    const int wid = threadIdx.x >> 6;
    const int wm = wid >> 1, wn = wid & 1;
    const int fr = lane & 15, g = lane >> 4;

    #pragma unroll
    for (int p = 0; p < 3; p++)
        #pragma unroll
        for (int j = 0; j < 3; j++) stage_u(Ag, Bg, K, bm, bn, p, lds + p*TILE, j);
    asm volatile("s_waitcnt vmcnt(6)" ::: "memory");
    __builtin_amdgcn_sched_barrier(0);
    __builtin_amdgcn_s_barrier();
    __builtin_amdgcn_sched_barrier(0);

    int cur = 0;
    for (int t = 0; t < NT; t++){
        short* buf = lds + cur*TILE;
        int sg = cur + 3; if (sg >= 4) sg -= 4;
        short* stg = lds + sg*TILE;
        short8 a[4], b[4];
        #pragma unroll
        for (int m = 0; m < 4; m++) a[m] = ld32(buf, wm*64 + m*16 + fr, g);
        #pragma unroll
        for (int n = 0; n < 4; n++) b[n] = ld32(buf, 256 + wn*64 + n*16 + fr, g);
        if (t + 3 < NT){
            stage_u(Ag, Bg, K, bm, bn, t+3, stg, 0);
            stage_u(Ag, Bg, K, bm, bn, t+3, stg, 1);
            stage_u(Ag, Bg, K, bm, bn, t+3, stg, 2);
        }
        __builtin_amdgcn_s_setprio(1);
        #pragma unroll
        for (int m = 0; m < 4; m++)
            #pragma unroll
            for (int n = 0; n < 4; n++)
                acc[m][n] = MFMA_BF16(a[m], b[n], acc[m][n]);
        __builtin_amdgcn_s_setprio(0);
        __builtin_amdgcn_sched_barrier(0);
        if (t + 3 < NT)      asm volatile("s_waitcnt vmcnt(6)" ::: "memory");
        else if (t + 2 < NT) asm volatile("s_waitcnt vmcnt(3)" ::: "memory");
        else if (t + 1 < NT) asm volatile("s_waitcnt vmcnt(0)" ::: "memory");
        __builtin_amdgcn_sched_barrier(0);
        __builtin_amdgcn_s_barrier();
        __builtin_amdgcn_sched_barrier(0);
        cur = cur + 1 == 4 ? 0 : cur + 1;
    }
}

// ---------------- GEMM1: hn[8192x1024] x W_in[5376x1024]^T, segmented epilogue ----------------
// Grid 32m x 42n = 1344 blocks; group-major (GN=6) for L2-resident B-panel slices.
__global__ __launch_bounds__(512, 4) void k_gemm1_g(const bf16* __restrict__ A,
                                                    const bf16* __restrict__ B,
                                                    bf16* __restrict__ z,
                                                    bf16* __restrict__ xp,
                                                    bf16* __restrict__ Bc,
                                                    bf16* __restrict__ Cc,
                                                    float* __restrict__ dtr){
    extern __shared__ short lds[];
    int wg = (blockIdx.x & 7)*168 + (blockIdx.x >> 3);   // 1344 = 8*168, bijective
    int grp = wg / 192, rem = wg % 192;                  // 7 groups of 6 n-tiles
    int nt_ = grp*6 + rem % 6;
    int mt_ = rem / 6;
    size_t bm = (size_t)mt_ * 256;
    size_t bn = (size_t)nt_ * 128;
    f32x4 acc[4][4] = {};
    gemm_main(A, B, D_MODEL, bm, bn, lds, acc);
    const int lane = threadIdx.x & 63;
    const int wid = threadIdx.x >> 6;
    const int wm = wid >> 1, wn = wid & 1;
    int cr = (lane >> 4)*4, cc = lane & 15;
    #pragma unroll
    for (int m = 0; m < 4; m++){
        size_t r0 = bm + wm*64 + m*16 + cr;
        #pragma unroll
        for (int n = 0; n < 4; n++){
            int c = (int)bn + wn*64 + n*16 + cc;
            #pragma unroll
            for (int j = 0; j < 4; j++){
                float v = acc[m][n][j];
                size_t r = r0 + j;
                if (c < O1)            z  [r * D_INNER + c]        = f2b(v);
                else if (c < O2)       xp [r * D_INNER + (c - O1)] = f2b(v);
                else if (c < O3)       Bc [r * 512 + (c - O2)]     = f2b(v);
                else if (c < O4)       Cc [r * 512 + (c - O3)]     = f2b(v);
                else if (c < PROJ_N)   dtr[r * 8 + (c - O4)]       = v;
            }
        }
    }
}

// ---------------- GEMM2: yg[8192x2048] x (W_out*g_out)[1024x2048]^T, row-scaled + residual ----------------
__global__ __launch_bounds__(512, 4) void k_gemm2_g(const bf16* __restrict__ A,
                                                    const bf16* __restrict__ B,
                                                    const float* __restrict__ res,
                                                    const float* __restrict__ sc,
                                                    float* __restrict__ C){
    extern __shared__ short lds[];
    int wg = (blockIdx.x & 7)*32 + (blockIdx.x >> 3);    // 256 = 8*32, bijective
    size_t bm = (size_t)(wg >> 3) * 256;                 // 32 m-tiles
    size_t bn = (size_t)(wg & 7) * 128;                  // 8 n-tiles
    f32x4 acc[4][4] = {};
    gemm_main_r4(A, B, D_INNER, bm, bn, lds, acc);
    const int lane = threadIdx.x & 63;
    const int wid = threadIdx.x >> 6;
    const int wm = wid >> 1, wn = wid & 1;
    int cr = (lane >> 4)*4, cc = lane & 15;
    #pragma unroll
    for (int m = 0; m < 4; m++){
        size_t r0 = bm + wm*64 + m*16 + cr;
        #pragma unroll
        for (int n = 0; n < 4; n++){
            size_t c = bn + wn*64 + n*16 + cc;
            #pragma unroll
            for (int j = 0; j < 4; j++){
                size_t r = r0 + j;
                C[r * D_MODEL + c] = acc[m][n][j]*sc[r] + res[r * D_MODEL + c];
            }
        }
    }
}

// ---------------- depthwise causal conv(4) + SiLU, s-parallel ----------------
__global__ __launch_bounds__(256) void k_conv_silu(const bf16* __restrict__ xp,
                                                   const float* __restrict__ cw,
                                                   const float* __restrict__ cb,
                                                   bf16* __restrict__ xout){
    int b = blockIdx.x;
    int c = blockIdx.y * 256 + threadIdx.x;
    int s0 = blockIdx.z * 32;
    float w0 = cw[c*4+0], w1 = cw[c*4+1], w2 = cw[c*4+2], w3 = cw[c*4+3];
    float bias = cb[c];
    const bf16* ib = xp + (size_t)b * SEQ * D_INNER + c;
    bf16* ob = xout + (size_t)b * SEQ * D_INNER + c;
    float x0 = 0.f, x1 = 0.f, x2 = 0.f;
    if (s0 >= 3){
        x0 = b2f(ib[(size_t)(s0-3) * D_INNER]);
        x1 = b2f(ib[(size_t)(s0-2) * D_INNER]);
        x2 = b2f(ib[(size_t)(s0-1) * D_INNER]);
    }
    #pragma unroll 4
    for (int s = s0; s < s0 + 32; s++){
        float x3 = b2f(ib[(size_t)s * D_INNER]);
        float a = x0*w0 + x1*w1 + x2*w2 + x3*w3 + bias;
        ob[(size_t)s * D_INNER] = f2b(silu_f(a));
        x0 = x1; x1 = x2; x2 = x3;
    }
}

// ---------------- dt_h -> logA cumsum (lcs) + tdec (prep folded in) ----------------
__global__ __launch_bounds__(64) void k_dt_lcs(const float* __restrict__ dtr,
                                               const float* __restrict__ W_dt,
                                               const float* __restrict__ b_dt,
                                               const float* __restrict__ A_log,
                                               float* __restrict__ lcs,
                                               float* __restrict__ tdec){
    __shared__ float sm[80];
    __shared__ float la[CHUNK][N_HEADS];
    int bc = blockIdx.x;
    int l = threadIdx.x;
    {
        int h = l >> 3, k = l & 7;
        float s = 0.f;
        for (int d = 0; d < HEAD_DIM; d++) s += W_dt[(size_t)(h*HEAD_DIM + d) * N_HEADS + k];
        sm[l] = s * (1.0f/(float)HEAD_DIM);
        if (l < 8){
            float sb = 0.f;
            for (int d = 0; d < HEAD_DIM; d++) sb += b_dt[l*HEAD_DIM + d];
            sm[64 + l] = sb * (1.0f/(float)HEAD_DIM);
            sm[72 + l] = -expf(A_log[l]);
        }
    }
    __syncthreads();
    const float* dr = dtr + (size_t)(bc*CHUNK + l) * 8;
    float d0 = dr[0], d1 = dr[1], d2 = dr[2], d3 = dr[3];
    float d4 = dr[4], d5 = dr[5], d6 = dr[6], d7 = dr[7];
    #pragma unroll
    for (int h = 0; h < 8; h++){
        float dt = sm[64+h]
                 + d0*sm[h*8+0] + d1*sm[h*8+1] + d2*sm[h*8+2] + d3*sm[h*8+3]
                 + d4*sm[h*8+4] + d5*sm[h*8+5] + d6*sm[h*8+6] + d7*sm[h*8+7];
        float sp = (dt > 20.f) ? dt : log1pf(expf(dt));
        la[l][h] = sp * sm[72+h];
    }
    __syncthreads();
    float out[8];
    #pragma unroll
    for (int h = 0; h < 8; h++) out[h] = 0.f;
    for (int l2 = 0; l2 <= l; l2++){
        #pragma unroll
        for (int h = 0; h < 8; h++) out[h] += la[l2][h];
    }
    float* lo = lcs + (size_t)(bc*CHUNK + l) * N_HEADS;
    #pragma unroll
    for (int h = 0; h < 8; h++) lo[h] = out[h];
    if (l == 63){
        #pragma unroll
        for (int h = 0; h < 8; h++) tdec[bc*N_HEADS + h] = expf(out[h]);
    }
}

// ================= fused chunked SSM + gate (silu(z)) in epilogue =================
#define LB   0
#define LC   4096
#define LGM  8192
#define LXT  12800
#define LSH  29184
#define LF   45568
#define LDS_BYTES 91904

__device__ __forceinline__ short8 frag_sw(const short* arr, int r, int k){
    return *(const short8*)(arr + r*64 + (k ^ ((r&7)<<3)));
}

__global__ __launch_bounds__(256, 1) void k_ssm(const bf16* __restrict__ Bc,
                                                const bf16* __restrict__ Cc,
                                                bf16* xg,
                                                const bf16* __restrict__ zg,
                                                const float* __restrict__ lcs,
                                                const float* __restrict__ tdec,
                                                const float* __restrict__ Dv){
    extern __shared__ short lds[];
    short* Blds  = lds + LB;
    short* Clds  = lds + LC;
    short* GMlds = lds + LGM;
    short* XTlds = lds + LXT;
    short* Shr   = lds + LSH;
    float* el = (float*)(lds + LF);
    float* ml = el + 64;
    float* ee = el + 128;

    const int tid = threadIdx.x;
    const int lane = tid & 63;
    const int wid = tid >> 6;
    const int fr = lane & 15;
    const int fk = (lane >> 4) * 8;
    const int r0 = (lane >> 4) * 4;
    const int b = blockIdx.x >> 3, h = blockIdx.x & 7;
    const float Dh = Dv[h];

    f32x4 carry[4][4] = {};

    for (int c = 0; c < NCHUNK; c++){
        const int bc = b*NCHUNK + c;
        __syncthreads();
        #pragma unroll
        for (int i = 0; i < 2; i++){
            int slot = i*256 + tid;
            int s = slot >> 3, u = slot & 7;
            size_t rb = (size_t)(bc*CHUNK + s) * 512 + h*64 + ((u ^ (s&7)) * 8);
            gl16(Bc + rb, Blds + slot*8);
            gl16(Cc + rb, Clds + slot*8);
        }
        #pragma unroll
        for (int i = 0; i < 8; i++){
            int slot = i*256 + tid;
            int s = slot >> 5, ck = slot & 31;
            gl16(xg + (size_t)(bc*CHUNK + s) * D_INNER + h*HEAD_DIM + ck*8, Shr + slot*8);
        }
        if (tid < 64) el[tid] = lcs[(size_t)(bc*CHUNK + tid) * N_HEADS + h];
        __syncthreads();
        if (tid < 64){
            float e63 = el[63];
            ml[tid] = expf(e63 - el[tid]);
            ee[tid] = expf(el[tid]);
        }
        #pragma unroll
        for (int i = 0; i < 8; i++){
            short8 t8;
            #pragma unroll
            for (int j = 0; j < 8; j++) t8[j] = Shr[(i*8 + j)*HEAD_DIM + tid];
            *(short8*)(XTlds + tid*64 + ((i*8) ^ ((tid&7)<<3))) = t8;
        }
        __syncthreads();
        {
            f32x4 accg[4] = {};
            #pragma unroll
            for (int kk = 0; kk < 2; kk++){
                short8 a = frag_sw(Clds, wid*16 + fr, kk*32 + fk);
                #pragma unroll
                for (int nt = 0; nt < 4; nt++){
                    short8 bb = frag_sw(Blds, nt*16 + fr, kk*32 + fk);
                    accg[nt] = __builtin_amdgcn_mfma_f32_16x16x32_bf16(a, bb, accg[nt], 0, 0, 0);
                }
            }
            #pragma unroll
            for (int nt = 0; nt < 4; nt++){
                int s = nt*16 + fr;
                float els = el[s];
                #pragma unroll
                for (int j = 0; j < 4; j++){
                    int l = wid*16 + r0 + j;
                    float f = (s <= l) ? expf(el[l] - els) : 0.f;
                    GMlds[l*72 + s] = f2s(accg[nt][j] * f);
                }
            }
            int crow = wid*16 + (lane >> 2), cq = lane & 3;
            float fe = ee[crow];
            #pragma unroll
            for (int half = 0; half < 2; half++){
                short8 v = *(short8*)(Clds + crow*64 + cq*16 + half*8);
                #pragma unroll
                for (int j = 0; j < 8; j++) v[j] = f2s(s2f(v[j]) * fe);
                *(short8*)(Clds + crow*64 + cq*16 + half*8) = v;
            }
        }
        #pragma unroll
        for (int mt = 0; mt < 4; mt++)
            #pragma unroll
            for (int nt = 0; nt < 4; nt++)
                #pragma unroll
                for (int j = 0; j < 4; j++){
                    int d = wid*64 + mt*16 + r0 + j;
                    int n = nt*16 + fr;
                    Shr[d*64 + (n ^ ((d&7)<<3))] = f2s(carry[mt][nt][j]);
                }
        float btv[16];
        {
            int bn_ = tid & 63, bq = tid >> 6;
            #pragma unroll
            for (int i = 0; i < 16; i++){
                int s = bq*16 + i;
                btv[i] = s2f(Blds[s*64 + (bn_ ^ ((s&7)<<3))]) * ml[s];
            }
        }
        __syncthreads();
        {
            int bn_ = tid & 63, bq = tid >> 6;
            #pragma unroll
            for (int i = 0; i < 16; i++){
                int s = bq*16 + i;
                Blds[bn_*64 + (s ^ ((bn_&7)<<3))] = f2s(btv[i]);
            }
        }
        {
            f32x4 accy[4][4] = {};
            #pragma unroll
            for (int kk = 0; kk < 2; kk++){
                short8 ag[4], ae[4], bx[4], bh[4];
                #pragma unroll
                for (int mt = 0; mt < 4; mt++){
                    ag[mt] = *(const short8*)(GMlds + (mt*16 + fr)*72 + kk*32 + fk);
                    ae[mt] = frag_sw(Clds, mt*16 + fr, kk*32 + fk);
                }
                #pragma unroll
                for (int nt = 0; nt < 4; nt++){
                    int d = wid*64 + nt*16 + fr;
                    bx[nt] = frag_sw(XTlds, d, kk*32 + fk);
                    bh[nt] = frag_sw(Shr,  d, kk*32 + fk);
                }
                #pragma unroll
                for (int mt = 0; mt < 4; mt++)
                    #pragma unroll
                    for (int nt = 0; nt < 4; nt++){
                        accy[mt][nt] = __builtin_amdgcn_mfma_f32_16x16x32_bf16(ag[mt], bx[nt], accy[mt][nt], 0, 0, 0);
                        accy[mt][nt] = __builtin_amdgcn_mfma_f32_16x16x32_bf16(ae[mt], bh[nt], accy[mt][nt], 0, 0, 0);
                    }
            }
            // epilogue: y = accy + x*Dh; gated = y*silu(z); write in place
            #pragma unroll
            for (int mt = 0; mt < 4; mt++)
                #pragma unroll
                for (int nt = 0; nt < 4; nt++){
                    int d = wid*64 + nt*16 + fr;
                    #pragma unroll
                    for (int j = 0; j < 4; j++){
                        int l = mt*16 + r0 + j;
                        float xv = s2f(XTlds[d*64 + (l ^ ((d&7)<<3))]);
                        size_t gi = (size_t)(bc*CHUNK + l) * D_INNER + h*HEAD_DIM + d;
                        float yv = accy[mt][nt][j] + xv*Dh;
                        float zv = b2f(zg[gi]);
                        xg[gi] = f2b(yv * silu_f(zv));
                    }
                }
        }
        __syncthreads();
        {
            f32x4 accs[4][4] = {};
            #pragma unroll
            for (int kk = 0; kk < 2; kk++){
                short8 ax[4], bt[4];
                #pragma unroll
                for (int mt = 0; mt < 4; mt++)
                    ax[mt] = frag_sw(XTlds, wid*64 + mt*16 + fr, kk*32 + fk);
                #pragma unroll
                for (int nt = 0; nt < 4; nt++)
                    bt[nt] = frag_sw(Blds, nt*16 + fr, kk*32 + fk);
                #pragma unroll
                for (int mt = 0; mt < 4; mt++)
                    #pragma unroll
                    for (int nt = 0; nt < 4; nt++)
                        accs[mt][nt] = __builtin_amdgcn_mfma_f32_16x16x32_bf16(ax[mt], bt[nt], accs[mt][nt], 0, 0, 0);
            }
            float td = tdec[bc*N_HEADS + h];
            #pragma unroll
            for (int mt = 0; mt < 4; mt++)
                #pragma unroll
                for (int nt = 0; nt < 4; nt++)
                    carry[mt][nt] = td * carry[mt][nt] + accs[mt][nt];
        }
    }
}

// ---------------- per-row rsqrt(mean(yg^2)+eps) ----------------
__global__ __launch_bounds__(256) void k_rowsc(const bf16* __restrict__ yg,
                                               float* __restrict__ sc){
    int row = blockIdx.x, t = threadIdx.x;
    union { uint4 u; bf16 b[8]; } v;
    v.u = ((const uint4*)(yg + (size_t)row * D_INNER))[t];
    float ss = 0.f;
    #pragma unroll
    for (int i = 0; i < 8; i++){
        float a = b2f(v.b[i]);
        ss += a*a;
    }
    ss = block_sum_256(ss);
    if (t == 0) sc[row] = rsqrtf(ss * (1.0f/(float)D_INNER) + EPSF);
}

extern "C" void kernel_launch(void* const* d_in, const int* in_sizes, int n_in,
                              void* d_out, int out_size, void* d_ws, size_t ws_size,
                              hipStream_t stream){
    const float* hidden = (const float*)d_in[0];
    const float* W_in   = (const float*)d_in[1];
    const float* conv_w = (const float*)d_in[2];
    const float* conv_b = (const float*)d_in[3];
    const float* W_dt   = (const float*)d_in[4];
    const float* b_dt   = (const float*)d_in[5];
    const float* A_log  = (const float*)d_in[6];
    const float* Dv     = (const float*)d_in[7];
    const float* W_out  = (const float*)d_in[8];
    const float* g_in   = (const float*)d_in[9];
    const float* g_out  = (const float*)d_in[10];

    // workspace layout (bytes) — total ~143.0 MiB
    char* ws = (char*)d_ws;
    bf16*  z    = (bf16*)(ws + 0);            // 33,554,432
    bf16*  xp   = (bf16*)(ws + 33554432);     // 33,554,432 (pre-conv x)
    bf16*  x    = (bf16*)(ws + 67108864);     // 33,554,432 (conv out; ssm writes gated y in place)
    bf16*  Bc   = (bf16*)(ws + 100663296);    //  8,388,608
    bf16*  Cc   = (bf16*)(ws + 109051904);    //  8,388,608
    float* dtr  = (float*)(ws + 117440512);   //    262,144
    float* lcs  = (float*)(ws + 117702656);   //    262,144
    float* tdec = (float*)(ws + 117964800);   //      4,096
    bf16*  Wb1  = (bf16*)(ws + 117969408);    // 11,010,048
    bf16*  hnb  = (bf16*)(ws + 128979456);    // 16,777,216
    bf16*  Wb2  = (bf16*)(ws + 145756672);    //  4,194,304
    float* sc   = (float*)(ws + 149950976);   //     32,768

    k_rms_in<<<ROWS, 256, 0, stream>>>(hidden, g_in, hnb);
    k_cvt_both<<<(N1 + D_MODEL*D_INNER)/1024, 256, 0, stream>>>(W_in, W_out, g_out, Wb1, Wb2);
    hipFuncSetAttribute((const void*)k_gemm1_g, hipFuncAttributeMaxDynamicSharedMemorySize, 73728);
    k_gemm1_g<<<(ROWS/256)*(PROJ_NPAD/128), 512, 73728, stream>>>(hnb, Wb1, z, xp, Bc, Cc, dtr);
    k_conv_silu<<<dim3(BATCH, D_INNER/256, SEQ/32), 256, 0, stream>>>(xp, conv_w, conv_b, x);
    k_dt_lcs<<<BATCH*NCHUNK, 64, 0, stream>>>(dtr, W_dt, b_dt, A_log, lcs, tdec);
    hipFuncSetAttribute((const void*)k_ssm, hipFuncAttributeMaxDynamicSharedMemorySize, LDS_BYTES);
    k_ssm<<<BATCH*N_HEADS, 256, LDS_BYTES, stream>>>(Bc, Cc, x, z, lcs, tdec, Dv);
    k_rowsc<<<ROWS, 256, 0, stream>>>(x, sc);
    hipFuncSetAttribute((const void*)k_gemm2_g, hipFuncAttributeMaxDynamicSharedMemorySize, 98304);
    k_gemm2_g<<<(ROWS/256)*(D_MODEL/128), 512, 98304, stream>>>(x, Wb2, hidden, sc, (float*)d_out);
}

// Round 15
// 281.578 us; speedup vs baseline: 1.1473x; 1.1473x over previous
//
#include <hip/hip_runtime.h>
#include <hip/hip_bf16.h>
#include <math.h>

typedef __hip_bfloat16 bf16;
typedef __attribute__((ext_vector_type(8))) short short8;
typedef __attribute__((ext_vector_type(4))) float f32x4;

#define AS1 __attribute__((address_space(1)))
#define AS3 __attribute__((address_space(3)))

#define D_MODEL 1024
#define D_INNER 2048
#define N_HEADS 8
#define D_STATE 64
#define CHUNK 64
#define HEAD_DIM 256
#define NCHUNK 4
#define BATCH 32
#define SEQ 256
#define ROWS (BATCH*SEQ)          // 8192
#define PROJ_N 5128
#define PROJ_NPAD 5376            // 42 tiles of 128
#define O1 D_INNER                // 2048
#define O2 (2*D_INNER)            // 4096
#define O3 (O2 + N_HEADS*D_STATE) // 4608
#define O4 (O3 + N_HEADS*D_STATE) // 5120
#define EPSF 1.1920929e-07f

__device__ __forceinline__ float silu_f(float x){ return x / (1.0f + expf(-x)); }
__device__ __forceinline__ float b2f(bf16 v){ return __bfloat162float(v); }
__device__ __forceinline__ bf16  f2b(float v){ return __float2bfloat16(v); }
__device__ __forceinline__ short f2s(float v){ bf16 b = __float2bfloat16(v); union{bf16 b; short s;} u; u.b=b; return u.s; }
__device__ __forceinline__ float s2f(short v){ union{short s; bf16 b;} u; u.s=v; return __bfloat162float(u.b); }

__device__ __forceinline__ void gl16(const void* g, void* l){
    __builtin_amdgcn_global_load_lds((const AS1 void*)g, (AS3 void*)l, 16, 0, 0);
}

__device__ __forceinline__ float block_sum_256(float v){
    __shared__ float sm[4];
    #pragma unroll
    for (int o = 32; o > 0; o >>= 1) v += __shfl_down(v, o, 64);
    int lane = threadIdx.x & 63, w = threadIdx.x >> 6;
    if (lane == 0) sm[w] = v;
    __syncthreads();
    return sm[0] + sm[1] + sm[2] + sm[3];
}

// ---------------- RMSNorm (input) -> bf16 ----------------
__global__ __launch_bounds__(256) void k_rms_in(const float* __restrict__ x,
                                                const float* __restrict__ g,
                                                bf16* __restrict__ out){
    int row = blockIdx.x, t = threadIdx.x;
    const float4* xr = (const float4*)(x + (size_t)row * D_MODEL);
    float4 v = xr[t];
    float ss = v.x*v.x + v.y*v.y + v.z*v.z + v.w*v.w;
    ss = block_sum_256(ss);
    float sc = rsqrtf(ss * (1.0f/(float)D_MODEL) + EPSF);
    float4 gv = ((const float4*)g)[t];
    union { ushort4 u; bf16 b[4]; } o;
    o.b[0] = f2b(v.x*sc*gv.x); o.b[1] = f2b(v.y*sc*gv.y);
    o.b[2] = f2b(v.z*sc*gv.z); o.b[3] = f2b(v.w*sc*gv.w);
    ((ushort4*)(out + (size_t)row * D_MODEL))[t] = o.u;
}

// ---------------- both weight casts in one launch ----------------
// region 1: W_in [5128x1024] -> Wb1 [5376x1024] bf16 zero-padded
// region 2: W_out[1024x2048] * g_out[k] -> Wb2 bf16 (g_out folded: exact, K-axis)
#define N1 (PROJ_NPAD*D_MODEL)
__global__ __launch_bounds__(256) void k_cvt_both(const float* __restrict__ W_in,
                                                  const float* __restrict__ W_out,
                                                  const float* __restrict__ g_out,
                                                  bf16* __restrict__ Wb1,
                                                  bf16* __restrict__ Wb2){
    int i = (blockIdx.x * 256 + threadIdx.x) * 4;
    union { ushort4 u; bf16 b[4]; } o;
    if (i < N1){
        int n_in = PROJ_N*D_MODEL;
        if (i + 3 < n_in){
            float4 v = *(const float4*)(W_in + i);
            o.b[0]=f2b(v.x); o.b[1]=f2b(v.y); o.b[2]=f2b(v.z); o.b[3]=f2b(v.w);
        } else {
            #pragma unroll
            for (int j = 0; j < 4; j++) o.b[j] = f2b((i+j < n_in) ? W_in[i+j] : 0.f);
        }
        *(ushort4*)(Wb1 + i) = o.u;
    } else {
        int k2 = i - N1;
        if (k2 < D_MODEL*D_INNER){
            float4 v = *(const float4*)(W_out + k2);
            float4 gv = *(const float4*)(g_out + (k2 & (D_INNER-1)));
            o.b[0]=f2b(v.x*gv.x); o.b[1]=f2b(v.y*gv.y); o.b[2]=f2b(v.z*gv.z); o.b[3]=f2b(v.w*gv.w);
            *(ushort4*)(Wb2 + k2) = o.u;
        }
    }
}

// ================= NT GEMM, 256x128 tile, 8 waves / 512 thr, BK=32 =================
// LDS slot (srow,s8) holds global (srow*2 + ((s8^(srow&7))>>2), kgrp (s8^(srow&7))&3).

__device__ __forceinline__ short8 ld32(const short* base, int row, int g){
    int sr = row >> 1;
    int e8 = (((row & 1) << 2) | g) ^ (sr & 7);
    return *(const short8*)(base + sr*64 + e8*8);
}

__device__ __forceinline__ void stage_u(const bf16* __restrict__ Ag,
                                        const bf16* __restrict__ Bg,
                                        int K, size_t bm, size_t bn, int t,
                                        short* buf, int j){
    const int tid = threadIdx.x;         // 512 threads
    const int wid = tid >> 6;
    int cidx = j*512 + tid;              // 0..1535 slot index
    int srow = cidx >> 3, s8 = cidx & 7;
    int eff = s8 ^ (srow & 7);
    int grow = srow*2 + (eff >> 2);      // 0..383
    int gcol = t*32 + (eff & 3)*8;
    const bf16* src = (grow < 256)
        ? Ag + (bm + grow) * (size_t)K + gcol
        : Bg + (bn + grow - 256) * (size_t)K + gcol;
    gl16(src, buf + (size_t)(j*512 + wid*64)*8);   // wave-uniform base + lane*16B
}

#define MFMA_BF16(A_,B_,C_) __builtin_amdgcn_mfma_f32_16x16x32_bf16(A_,B_,C_,0,0,0)

// ---- ring-3 (72 KB), per-wave 64x64 — R9 proven (gemm1) ----
__device__ __forceinline__ void gemm_main(const bf16* __restrict__ Ag,
                                          const bf16* __restrict__ Bg,
                                          int K, size_t bm, size_t bn,
                                          short* lds, f32x4 (&acc)[4][4]){
    constexpr int TILE = 384*32;
    const int NT = K >> 5;
    const int lane = threadIdx.x & 63;
    const int wid = threadIdx.x >> 6;
    const int wm = wid >> 1, wn = wid & 1;
    const int fr = lane & 15, g = lane >> 4;

    #pragma unroll
    for (int j = 0; j < 3; j++) stage_u(Ag, Bg, K, bm, bn, 0, lds, j);
    #pragma unroll
    for (int j = 0; j < 3; j++) stage_u(Ag, Bg, K, bm, bn, 1, lds + TILE, j);
    asm volatile("s_waitcnt vmcnt(3)" ::: "memory");
    __builtin_amdgcn_sched_barrier(0);
    __builtin_amdgcn_s_barrier();
    __builtin_amdgcn_sched_barrier(0);

    int cur = 0;
    for (int t = 0; t < NT; t++){
        short* buf = lds + cur*TILE;
        int sg = cur + 2; if (sg >= 3) sg -= 3;
        short* stg = lds + sg*TILE;
        short8 a[4], b[4];
        #pragma unroll
        for (int m = 0; m < 4; m++) a[m] = ld32(buf, wm*64 + m*16 + fr, g);
        #pragma unroll
        for (int n = 0; n < 4; n++) b[n] = ld32(buf, 256 + wn*64 + n*16 + fr, g);
        if (t + 2 < NT){
            stage_u(Ag, Bg, K, bm, bn, t+2, stg, 0);
            stage_u(Ag, Bg, K, bm, bn, t+2, stg, 1);
            stage_u(Ag, Bg, K, bm, bn, t+2, stg, 2);
        }
        __builtin_amdgcn_s_setprio(1);
        #pragma unroll
        for (int m = 0; m < 4; m++)
            #pragma unroll
            for (int n = 0; n < 4; n++)
                acc[m][n] = MFMA_BF16(a[m], b[n], acc[m][n]);
        __builtin_amdgcn_s_setprio(0);
        __builtin_amdgcn_sched_barrier(0);
        if (t + 2 < NT)      asm volatile("s_waitcnt vmcnt(3)" ::: "memory");
        else if (t + 1 < NT) asm volatile("s_waitcnt vmcnt(0)" ::: "memory");
        __builtin_amdgcn_sched_barrier(0);
        __builtin_amdgcn_s_barrier();
        __builtin_amdgcn_sched_barrier(0);
        cur = cur + 1 == 3 ? 0 : cur + 1;
    }
}

// ---- ring-4 (96 KB), deeper prefetch for gemm2 (grid-capped at 1 block/CU) ----
__device__ __forceinline__ void gemm_main_r4(const bf16* __restrict__ Ag,
                                             const bf16* __restrict__ Bg,
                                             int K, size_t bm, size_t bn,
                                             short* lds, f32x4 (&acc)[4][4]){
    constexpr int TILE = 384*32;
    const int NT = K >> 5;
    const int lane = threadIdx.x & 63;
    const int wid = threadIdx.x >> 6;
    const int wm = wid >> 1, wn = wid & 1;
    const int fr = lane & 15, g = lane >> 4;

    #pragma unroll
    for (int p = 0; p < 3; p++)
        #pragma unroll
        for (int j = 0; j < 3; j++) stage_u(Ag, Bg, K, bm, bn, p, lds + p*TILE, j);
    asm volatile("s_waitcnt vmcnt(6)" ::: "memory");
    __builtin_amdgcn_sched_barrier(0);
    __builtin_amdgcn_s_barrier();
    __builtin_amdgcn_sched_barrier(0);

    int cur = 0;
    for (int t = 0; t < NT; t++){
        short* buf = lds + cur*TILE;
        int sg = cur + 3; if (sg >= 4) sg -= 4;
        short* stg = lds + sg*TILE;
        short8 a[4], b[4];
        #pragma unroll
        for (int m = 0; m < 4; m++) a[m] = ld32(buf, wm*64 + m*16 + fr, g);
        #pragma unroll
        for (int n = 0; n < 4; n++) b[n] = ld32(buf, 256 + wn*64 + n*16 + fr, g);
        if (t + 3 < NT){
            stage_u(Ag, Bg, K, bm, bn, t+3, stg, 0);
            stage_u(Ag, Bg, K, bm, bn, t+3, stg, 1);
            stage_u(Ag, Bg, K, bm, bn, t+3, stg, 2);
        }
        __builtin_amdgcn_s_setprio(1);
        #pragma unroll
        for (int m = 0; m < 4; m++)
            #pragma unroll
            for (int n = 0; n < 4; n++)
                acc[m][n] = MFMA_BF16(a[m], b[n], acc[m][n]);
        __builtin_amdgcn_s_setprio(0);
        __builtin_amdgcn_sched_barrier(0);
        if (t + 3 < NT)      asm volatile("s_waitcnt vmcnt(6)" ::: "memory");
        else if (t + 2 < NT) asm volatile("s_waitcnt vmcnt(3)" ::: "memory");
        else if (t + 1 < NT) asm volatile("s_waitcnt vmcnt(0)" ::: "memory");
        __builtin_amdgcn_sched_barrier(0);
        __builtin_amdgcn_s_barrier();
        __builtin_amdgcn_sched_barrier(0);
        cur = cur + 1 == 4 ? 0 : cur + 1;
    }
}

// ---------------- GEMM1: hn[8192x1024] x W_in[5376x1024]^T, segmented epilogue ----------------
// Grid 32m x 42n = 1344 blocks; group-major (GN=6) for L2-resident B-panel slices.
__global__ __launch_bounds__(512, 4) void k_gemm1_g(const bf16* __restrict__ A,
                                                    const bf16* __restrict__ B,
                                                    bf16* __restrict__ z,
                                                    bf16* __restrict__ xp,
                                                    bf16* __restrict__ Bc,
                                                    bf16* __restrict__ Cc,
                                                    float* __restrict__ dtr){
    extern __shared__ short lds[];
    int wg = (blockIdx.x & 7)*168 + (blockIdx.x >> 3);   // 1344 = 8*168, bijective
    int grp = wg / 192, rem = wg % 192;                  // 7 groups of 6 n-tiles
    int nt_ = grp*6 + rem % 6;
    int mt_ = rem / 6;
    size_t bm = (size_t)mt_ * 256;
    size_t bn = (size_t)nt_ * 128;
    f32x4 acc[4][4] = {};
    gemm_main(A, B, D_MODEL, bm, bn, lds, acc);
    const int lane = threadIdx.x & 63;
    const int wid = threadIdx.x >> 6;
    const int wm = wid >> 1, wn = wid & 1;
    int cr = (lane >> 4)*4, cc = lane & 15;
    #pragma unroll
    for (int m = 0; m < 4; m++){
        size_t r0 = bm + wm*64 + m*16 + cr;
        #pragma unroll
        for (int n = 0; n < 4; n++){
            int c = (int)bn + wn*64 + n*16 + cc;
            #pragma unroll
            for (int j = 0; j < 4; j++){
                float v = acc[m][n][j];
                size_t r = r0 + j;
                if (c < O1)            z  [r * D_INNER + c]        = f2b(v);
                else if (c < O2)       xp [r * D_INNER + (c - O1)] = f2b(v);
                else if (c < O3)       Bc [r * 512 + (c - O2)]     = f2b(v);
                else if (c < O4)       Cc [r * 512 + (c - O3)]     = f2b(v);
                else if (c < PROJ_N)   dtr[r * 8 + (c - O4)]       = v;
            }
        }
    }
}

// ---------------- GEMM2: yn[8192x2048] x (W_out*g_out)[1024x2048]^T + hidden -> f32 ----------------
__global__ __launch_bounds__(512, 4) void k_gemm2_g(const bf16* __restrict__ A,
                                                    const bf16* __restrict__ B,
                                                    const float* __restrict__ res,
                                                    float* __restrict__ C){
    extern __shared__ short lds[];
    int wg = (blockIdx.x & 7)*32 + (blockIdx.x >> 3);    // 256 = 8*32, bijective
    size_t bm = (size_t)(wg >> 3) * 256;                 // 32 m-tiles
    size_t bn = (size_t)(wg & 7) * 128;                  // 8 n-tiles
    f32x4 acc[4][4] = {};
    gemm_main_r4(A, B, D_INNER, bm, bn, lds, acc);
    const int lane = threadIdx.x & 63;
    const int wid = threadIdx.x >> 6;
    const int wm = wid >> 1, wn = wid & 1;
    int cr = (lane >> 4)*4, cc = lane & 15;
    #pragma unroll
    for (int m = 0; m < 4; m++){
        size_t r0 = bm + wm*64 + m*16 + cr;
        #pragma unroll
        for (int n = 0; n < 4; n++){
            size_t c = bn + wn*64 + n*16 + cc;
            #pragma unroll
            for (int j = 0; j < 4; j++){
                size_t r = r0 + j;
                C[r * D_MODEL + c] = acc[m][n][j] + res[r * D_MODEL + c];
            }
        }
    }
}

// ---------------- depthwise causal conv(4) + SiLU, s-parallel ----------------
__global__ __launch_bounds__(256) void k_conv_silu(const bf16* __restrict__ xp,
                                                   const float* __restrict__ cw,
                                                   const float* __restrict__ cb,
                                                   bf16* __restrict__ xout){
    int b = blockIdx.x;
    int c = blockIdx.y * 256 + threadIdx.x;
    int s0 = blockIdx.z * 32;
    float w0 = cw[c*4+0], w1 = cw[c*4+1], w2 = cw[c*4+2], w3 = cw[c*4+3];
    float bias = cb[c];
    const bf16* ib = xp + (size_t)b * SEQ * D_INNER + c;
    bf16* ob = xout + (size_t)b * SEQ * D_INNER + c;
    float x0 = 0.f, x1 = 0.f, x2 = 0.f;
    if (s0 >= 3){
        x0 = b2f(ib[(size_t)(s0-3) * D_INNER]);
        x1 = b2f(ib[(size_t)(s0-2) * D_INNER]);
        x2 = b2f(ib[(size_t)(s0-1) * D_INNER]);
    }
    #pragma unroll 4
    for (int s = s0; s < s0 + 32; s++){
        float x3 = b2f(ib[(size_t)s * D_INNER]);
        float a = x0*w0 + x1*w1 + x2*w2 + x3*w3 + bias;
        ob[(size_t)s * D_INNER] = f2b(silu_f(a));
        x0 = x1; x1 = x2; x2 = x3;
    }
}

// ---------------- dt_h -> logA cumsum (lcs) + tdec (prep folded in) ----------------
__global__ __launch_bounds__(64) void k_dt_lcs(const float* __restrict__ dtr,
                                               const float* __restrict__ W_dt,
                                               const float* __restrict__ b_dt,
                                               const float* __restrict__ A_log,
                                               float* __restrict__ lcs,
                                               float* __restrict__ tdec){
    __shared__ float sm[80];
    __shared__ float la[CHUNK][N_HEADS];
    int bc = blockIdx.x;
    int l = threadIdx.x;
    {
        int h = l >> 3, k = l & 7;
        float s = 0.f;
        for (int d = 0; d < HEAD_DIM; d++) s += W_dt[(size_t)(h*HEAD_DIM + d) * N_HEADS + k];
        sm[l] = s * (1.0f/(float)HEAD_DIM);
        if (l < 8){
            float sb = 0.f;
            for (int d = 0; d < HEAD_DIM; d++) sb += b_dt[l*HEAD_DIM + d];
            sm[64 + l] = sb * (1.0f/(float)HEAD_DIM);
            sm[72 + l] = -expf(A_log[l]);
        }
    }
    __syncthreads();
    const float* dr = dtr + (size_t)(bc*CHUNK + l) * 8;
    float d0 = dr[0], d1 = dr[1], d2 = dr[2], d3 = dr[3];
    float d4 = dr[4], d5 = dr[5], d6 = dr[6], d7 = dr[7];
    #pragma unroll
    for (int h = 0; h < 8; h++){
        float dt = sm[64+h]
                 + d0*sm[h*8+0] + d1*sm[h*8+1] + d2*sm[h*8+2] + d3*sm[h*8+3]
                 + d4*sm[h*8+4] + d5*sm[h*8+5] + d6*sm[h*8+6] + d7*sm[h*8+7];
        float sp = (dt > 20.f) ? dt : log1pf(expf(dt));
        la[l][h] = sp * sm[72+h];
    }
    __syncthreads();
    float out[8];
    #pragma unroll
    for (int h = 0; h < 8; h++) out[h] = 0.f;
    for (int l2 = 0; l2 <= l; l2++){
        #pragma unroll
        for (int h = 0; h < 8; h++) out[h] += la[l2][h];
    }
    float* lo = lcs + (size_t)(bc*CHUNK + l) * N_HEADS;
    #pragma unroll
    for (int h = 0; h < 8; h++) lo[h] = out[h];
    if (l == 63){
        #pragma unroll
        for (int h = 0; h < 8; h++) tdec[bc*N_HEADS + h] = expf(out[h]);
    }
}

// ================= fused chunked SSM (round-4/R12, verified) =================
#define LB   0
#define LC   4096
#define LGM  8192
#define LXT  12800
#define LSH  29184
#define LF   45568
#define LDS_BYTES 91904

__device__ __forceinline__ short8 frag_sw(const short* arr, int r, int k){
    return *(const short8*)(arr + r*64 + (k ^ ((r&7)<<3)));
}

__global__ __launch_bounds__(256, 1) void k_ssm(const bf16* __restrict__ Bc,
                                                const bf16* __restrict__ Cc,
                                                bf16* xg,
                                                const float* __restrict__ lcs,
                                                const float* __restrict__ tdec,
                                                const float* __restrict__ Dv){
    extern __shared__ short lds[];
    short* Blds  = lds + LB;
    short* Clds  = lds + LC;
    short* GMlds = lds + LGM;
    short* XTlds = lds + LXT;
    short* Shr   = lds + LSH;
    float* el = (float*)(lds + LF);
    float* ml = el + 64;
    float* ee = el + 128;

    const int tid = threadIdx.x;
    const int lane = tid & 63;
    const int wid = tid >> 6;
    const int fr = lane & 15;
    const int fk = (lane >> 4) * 8;
    const int r0 = (lane >> 4) * 4;
    const int b = blockIdx.x >> 3, h = blockIdx.x & 7;
    const float Dh = Dv[h];

    f32x4 carry[4][4] = {};

    for (int c = 0; c < NCHUNK; c++){
        const int bc = b*NCHUNK + c;
        __syncthreads();
        #pragma unroll
        for (int i = 0; i < 2; i++){
            int slot = i*256 + tid;
            int s = slot >> 3, u = slot & 7;
            size_t rb = (size_t)(bc*CHUNK + s) * 512 + h*64 + ((u ^ (s&7)) * 8);
            gl16(Bc + rb, Blds + slot*8);
            gl16(Cc + rb, Clds + slot*8);
        }
        #pragma unroll
        for (int i = 0; i < 8; i++){
            int slot = i*256 + tid;
            int s = slot >> 5, ck = slot & 31;
            gl16(xg + (size_t)(bc*CHUNK + s) * D_INNER + h*HEAD_DIM + ck*8, Shr + slot*8);
        }
        if (tid < 64) el[tid] = lcs[(size_t)(bc*CHUNK + tid) * N_HEADS + h];
        __syncthreads();
        if (tid < 64){
            float e63 = el[63];
            ml[tid] = expf(e63 - el[tid]);
            ee[tid] = expf(el[tid]);
        }
        #pragma unroll
        for (int i = 0; i < 8; i++){
            short8 t8;
            #pragma unroll
            for (int j = 0; j < 8; j++) t8[j] = Shr[(i*8 + j)*HEAD_DIM + tid];
            *(short8*)(XTlds + tid*64 + ((i*8) ^ ((tid&7)<<3))) = t8;
        }
        __syncthreads();
        {
            f32x4 accg[4] = {};
            #pragma unroll
            for (int kk = 0; kk < 2; kk++){
                short8 a = frag_sw(Clds, wid*16 + fr, kk*32 + fk);
                #pragma unroll
                for (int nt = 0; nt < 4; nt++){
                    short8 bb = frag_sw(Blds, nt*16 + fr, kk*32 + fk);
                    accg[nt] = __builtin_amdgcn_mfma_f32_16x16x32_bf16(a, bb, accg[nt], 0, 0, 0);
                }
            }
            #pragma unroll
            for (int nt = 0; nt < 4; nt++){
                int s = nt*16 + fr;
                float els = el[s];
                #pragma unroll
                for (int j = 0; j < 4; j++){
                    int l = wid*16 + r0 + j;
                    float f = (s <= l) ? expf(el[l] - els) : 0.f;
                    GMlds[l*72 + s] = f2s(accg[nt][j] * f);
                }
            }
            int crow = wid*16 + (lane >> 2), cq = lane & 3;
            float fe = ee[crow];
            #pragma unroll
            for (int half = 0; half < 2; half++){
                short8 v = *(short8*)(Clds + crow*64 + cq*16 + half*8);
                #pragma unroll
                for (int j = 0; j < 8; j++) v[j] = f2s(s2f(v[j]) * fe);
                *(short8*)(Clds + crow*64 + cq*16 + half*8) = v;
            }
        }
        #pragma unroll
        for (int mt = 0; mt < 4; mt++)
            #pragma unroll
            for (int nt = 0; nt < 4; nt++)
                #pragma unroll
                for (int j = 0; j < 4; j++){
                    int d = wid*64 + mt*16 + r0 + j;
                    int n = nt*16 + fr;
                    Shr[d*64 + (n ^ ((d&7)<<3))] = f2s(carry[mt][nt][j]);
                }
        float btv[16];
        {
            int bn_ = tid & 63, bq = tid >> 6;
            #pragma unroll
            for (int i = 0; i < 16; i++){
                int s = bq*16 + i;
                btv[i] = s2f(Blds[s*64 + (bn_ ^ ((s&7)<<3))]) * ml[s];
            }
        }
        __syncthreads();
        {
            int bn_ = tid & 63, bq = tid >> 6;
            #pragma unroll
            for (int i = 0; i < 16; i++){
                int s = bq*16 + i;
                Blds[bn_*64 + (s ^ ((bn_&7)<<3))] = f2s(btv[i]);
            }
        }
        {
            f32x4 accy[4][4] = {};
            #pragma unroll
            for (int kk = 0; kk < 2; kk++){
                short8 ag[4], ae[4], bx[4], bh[4];
                #pragma unroll
                for (int mt = 0; mt < 4; mt++){
                    ag[mt] = *(const short8*)(GMlds + (mt*16 + fr)*72 + kk*32 + fk);
                    ae[mt] = frag_sw(Clds, mt*16 + fr, kk*32 + fk);
                }
                #pragma unroll
                for (int nt = 0; nt < 4; nt++){
                    int d = wid*64 + nt*16 + fr;
                    bx[nt] = frag_sw(XTlds, d, kk*32 + fk);
                    bh[nt] = frag_sw(Shr,  d, kk*32 + fk);
                }
                #pragma unroll
                for (int mt = 0; mt < 4; mt++)
                    #pragma unroll
                    for (int nt = 0; nt < 4; nt++){
                        accy[mt][nt] = __builtin_amdgcn_mfma_f32_16x16x32_bf16(ag[mt], bx[nt], accy[mt][nt], 0, 0, 0);
                        accy[mt][nt] = __builtin_amdgcn_mfma_f32_16x16x32_bf16(ae[mt], bh[nt], accy[mt][nt], 0, 0, 0);
                    }
            }
            #pragma unroll
            for (int mt = 0; mt < 4; mt++)
                #pragma unroll
                for (int nt = 0; nt < 4; nt++){
                    int d = wid*64 + nt*16 + fr;
                    #pragma unroll
                    for (int j = 0; j < 4; j++){
                        int l = mt*16 + r0 + j;
                        float xv = s2f(XTlds[d*64 + (l ^ ((d&7)<<3))]);
                        xg[(size_t)(bc*CHUNK + l) * D_INNER + h*HEAD_DIM + d] = f2b(accy[mt][nt][j] + xv*Dh);
                    }
                }
        }
        __syncthreads();
        {
            f32x4 accs[4][4] = {};
            #pragma unroll
            for (int kk = 0; kk < 2; kk++){
                short8 ax[4], bt[4];
                #pragma unroll
                for (int mt = 0; mt < 4; mt++)
                    ax[mt] = frag_sw(XTlds, wid*64 + mt*16 + fr, kk*32 + fk);
                #pragma unroll
                for (int nt = 0; nt < 4; nt++)
                    bt[nt] = frag_sw(Blds, nt*16 + fr, kk*32 + fk);
                #pragma unroll
                for (int mt = 0; mt < 4; mt++)
                    #pragma unroll
                    for (int nt = 0; nt < 4; nt++)
                        accs[mt][nt] = __builtin_amdgcn_mfma_f32_16x16x32_bf16(ax[mt], bt[nt], accs[mt][nt], 0, 0, 0);
            }
            float td = tdec[bc*N_HEADS + h];
            #pragma unroll
            for (int mt = 0; mt < 4; mt++)
                #pragma unroll
                for (int nt = 0; nt < 4; nt++)
                    carry[mt][nt] = td * carry[mt][nt] + accs[mt][nt];
        }
    }
}

// ---------------- gate with silu(z) + RMSNorm (g_out folded into Wb2) -> yn bf16 ----------------
__global__ __launch_bounds__(256) void k_gate_rms(const bf16* __restrict__ y,
                                                  const bf16* __restrict__ z,
                                                  bf16* __restrict__ yn){
    int row = blockIdx.x, t = threadIdx.x;
    union { uint4 u; bf16 b[8]; } yv, zv, ov;
    yv.u = ((const uint4*)(y + (size_t)row * D_INNER))[t];
    zv.u = ((const uint4*)(z + (size_t)row * D_INNER))[t];
    float v[8];
    float ss = 0.f;
    #pragma unroll
    for (int i = 0; i < 8; i++){
        float a = b2f(yv.b[i]);
        float q = b2f(zv.b[i]);
        v[i] = a * silu_f(q);
        ss += v[i]*v[i];
    }
    ss = block_sum_256(ss);
    float sc = rsqrtf(ss * (1.0f/(float)D_INNER) + EPSF);
    #pragma unroll
    for (int i = 0; i < 8; i++) ov.b[i] = f2b(v[i]*sc);
    ((uint4*)(yn + (size_t)row * D_INNER))[t] = ov.u;
}

extern "C" void kernel_launch(void* const* d_in, const int* in_sizes, int n_in,
                              void* d_out, int out_size, void* d_ws, size_t ws_size,
                              hipStream_t stream){
    const float* hidden = (const float*)d_in[0];
    const float* W_in   = (const float*)d_in[1];
    const float* conv_w = (const float*)d_in[2];
    const float* conv_b = (const float*)d_in[3];
    const float* W_dt   = (const float*)d_in[4];
    const float* b_dt   = (const float*)d_in[5];
    const float* A_log  = (const float*)d_in[6];
    const float* Dv     = (const float*)d_in[7];
    const float* W_out  = (const float*)d_in[8];
    const float* g_in   = (const float*)d_in[9];
    const float* g_out  = (const float*)d_in[10];

    // workspace layout (bytes) — total ~150.0 MiB
    char* ws = (char*)d_ws;
    bf16*  z    = (bf16*)(ws + 0);            // 33,554,432
    bf16*  xp   = (bf16*)(ws + 33554432);     // 33,554,432 (pre-conv x; reused as yn)
    bf16*  x    = (bf16*)(ws + 67108864);     // 33,554,432 (conv out; ssm writes y in place)
    bf16*  Bc   = (bf16*)(ws + 100663296);    //  8,388,608
    bf16*  Cc   = (bf16*)(ws + 109051904);    //  8,388,608
    float* dtr  = (float*)(ws + 117440512);   //    262,144
    float* lcs  = (float*)(ws + 117702656);   //    262,144
    float* tdec = (float*)(ws + 117964800);   //      4,096
    bf16*  Wb1  = (bf16*)(ws + 117969408);    // 11,010,048
    bf16*  hnb  = (bf16*)(ws + 128979456);    // 16,777,216
    bf16*  Wb2  = (bf16*)(ws + 145756672);    //  4,194,304
    bf16*  yn   = xp;                          // xp dead after conv

    k_rms_in<<<ROWS, 256, 0, stream>>>(hidden, g_in, hnb);
    k_cvt_both<<<(N1 + D_MODEL*D_INNER)/1024, 256, 0, stream>>>(W_in, W_out, g_out, Wb1, Wb2);
    hipFuncSetAttribute((const void*)k_gemm1_g, hipFuncAttributeMaxDynamicSharedMemorySize, 73728);
    k_gemm1_g<<<(ROWS/256)*(PROJ_NPAD/128), 512, 73728, stream>>>(hnb, Wb1, z, xp, Bc, Cc, dtr);
    k_conv_silu<<<dim3(BATCH, D_INNER/256, SEQ/32), 256, 0, stream>>>(xp, conv_w, conv_b, x);
    k_dt_lcs<<<BATCH*NCHUNK, 64, 0, stream>>>(dtr, W_dt, b_dt, A_log, lcs, tdec);
    hipFuncSetAttribute((const void*)k_ssm, hipFuncAttributeMaxDynamicSharedMemorySize, LDS_BYTES);
    k_ssm<<<BATCH*N_HEADS, 256, LDS_BYTES, stream>>>(Bc, Cc, x, lcs, tdec, Dv);
    k_gate_rms<<<ROWS, 256, 0, stream>>>(x, z, yn);
    hipFuncSetAttribute((const void*)k_gemm2_g, hipFuncAttributeMaxDynamicSharedMemorySize, 98304);
    k_gemm2_g<<<(ROWS/256)*(D_MODEL/128), 512, 98304, stream>>>(yn, Wb2, hidden, (float*)d_out);
}

// Round 16
// 265.297 us; speedup vs baseline: 1.2177x; 1.0614x over previous
//
#include <hip/hip_runtime.h>
#include <hip/hip_bf16.h>
#include <math.h>

typedef __hip_bfloat16 bf16;
typedef __attribute__((ext_vector_type(8))) short short8;
typedef __attribute__((ext_vector_type(4))) float f32x4;

#define AS1 __attribute__((address_space(1)))
#define AS3 __attribute__((address_space(3)))

#define D_MODEL 1024
#define D_INNER 2048
#define N_HEADS 8
#define D_STATE 64
#define CHUNK 64
#define HEAD_DIM 256
#define NCHUNK 4
#define BATCH 32
#define SEQ 256
#define ROWS (BATCH*SEQ)          // 8192
#define PROJ_N 5128
#define PROJ_NPAD 5376            // 42 tiles of 128
#define O1 D_INNER                // 2048
#define O2 (2*D_INNER)            // 4096
#define O3 (O2 + N_HEADS*D_STATE) // 4608
#define O4 (O3 + N_HEADS*D_STATE) // 5120
#define EPSF 1.1920929e-07f

__device__ __forceinline__ float silu_f(float x){ return x / (1.0f + expf(-x)); }
__device__ __forceinline__ float b2f(bf16 v){ return __bfloat162float(v); }
__device__ __forceinline__ bf16  f2b(float v){ return __float2bfloat16(v); }
__device__ __forceinline__ short f2s(float v){ bf16 b = __float2bfloat16(v); union{bf16 b; short s;} u; u.b=b; return u.s; }
__device__ __forceinline__ float s2f(short v){ union{short s; bf16 b;} u; u.s=v; return __bfloat162float(u.b); }

__device__ __forceinline__ void gl16(const void* g, void* l){
    __builtin_amdgcn_global_load_lds((const AS1 void*)g, (AS3 void*)l, 16, 0, 0);
}

__device__ __forceinline__ float block_sum_256(float v){
    __shared__ float sm[4];
    #pragma unroll
    for (int o = 32; o > 0; o >>= 1) v += __shfl_down(v, o, 64);
    int lane = threadIdx.x & 63, w = threadIdx.x >> 6;
    if (lane == 0) sm[w] = v;
    __syncthreads();
    return sm[0] + sm[1] + sm[2] + sm[3];
}

// ---------------- RMSNorm (input) -> bf16 ----------------
__global__ __launch_bounds__(256) void k_rms_in(const float* __restrict__ x,
                                                const float* __restrict__ g,
                                                bf16* __restrict__ out){
    int row = blockIdx.x, t = threadIdx.x;
    const float4* xr = (const float4*)(x + (size_t)row * D_MODEL);
    float4 v = xr[t];
    float ss = v.x*v.x + v.y*v.y + v.z*v.z + v.w*v.w;
    ss = block_sum_256(ss);
    float sc = rsqrtf(ss * (1.0f/(float)D_MODEL) + EPSF);
    float4 gv = ((const float4*)g)[t];
    union { ushort4 u; bf16 b[4]; } o;
    o.b[0] = f2b(v.x*sc*gv.x); o.b[1] = f2b(v.y*sc*gv.y);
    o.b[2] = f2b(v.z*sc*gv.z); o.b[3] = f2b(v.w*sc*gv.w);
    ((ushort4*)(out + (size_t)row * D_MODEL))[t] = o.u;
}

// ---------------- both weight casts in one launch ----------------
// region 1: W_in [5128x1024] -> Wb1 [5376x1024] bf16 zero-padded
// region 2: W_out[1024x2048] * g_out[k] -> Wb2 bf16 (g_out folded: exact, K-axis)
#define N1 (PROJ_NPAD*D_MODEL)
__global__ __launch_bounds__(256) void k_cvt_both(const float* __restrict__ W_in,
                                                  const float* __restrict__ W_out,
                                                  const float* __restrict__ g_out,
                                                  bf16* __restrict__ Wb1,
                                                  bf16* __restrict__ Wb2){
    int i = (blockIdx.x * 256 + threadIdx.x) * 4;
    union { ushort4 u; bf16 b[4]; } o;
    if (i < N1){
        int n_in = PROJ_N*D_MODEL;
        if (i + 3 < n_in){
            float4 v = *(const float4*)(W_in + i);
            o.b[0]=f2b(v.x); o.b[1]=f2b(v.y); o.b[2]=f2b(v.z); o.b[3]=f2b(v.w);
        } else {
            #pragma unroll
            for (int j = 0; j < 4; j++) o.b[j] = f2b((i+j < n_in) ? W_in[i+j] : 0.f);
        }
        *(ushort4*)(Wb1 + i) = o.u;
    } else {
        int k2 = i - N1;
        if (k2 < D_MODEL*D_INNER){
            float4 v = *(const float4*)(W_out + k2);
            float4 gv = *(const float4*)(g_out + (k2 & (D_INNER-1)));
            o.b[0]=f2b(v.x*gv.x); o.b[1]=f2b(v.y*gv.y); o.b[2]=f2b(v.z*gv.z); o.b[3]=f2b(v.w*gv.w);
            *(ushort4*)(Wb2 + k2) = o.u;
        }
    }
}

// ================= NT GEMM, 256x128 tile, 8 waves / 512 thr, BK=32, ring-3 =================
// LDS slot (srow,s8) holds global (srow*2 + ((s8^(srow&7))>>2), kgrp (s8^(srow&7))&3).

__device__ __forceinline__ short8 ld32(const short* base, int row, int g){
    int sr = row >> 1;
    int e8 = (((row & 1) << 2) | g) ^ (sr & 7);
    return *(const short8*)(base + sr*64 + e8*8);
}

__device__ __forceinline__ void stage_u(const bf16* __restrict__ Ag,
                                        const bf16* __restrict__ Bg,
                                        int K, size_t bm, size_t bn, int t,
                                        short* buf, int j){
    const int tid = threadIdx.x;         // 512 threads
    const int wid = tid >> 6;
    int cidx = j*512 + tid;              // 0..1535 slot index
    int srow = cidx >> 3, s8 = cidx & 7;
    int eff = s8 ^ (srow & 7);
    int grow = srow*2 + (eff >> 2);      // 0..383
    int gcol = t*32 + (eff & 3)*8;
    const bf16* src = (grow < 256)
        ? Ag + (bm + grow) * (size_t)K + gcol
        : Bg + (bn + grow - 256) * (size_t)K + gcol;
    gl16(src, buf + (size_t)(j*512 + wid*64)*8);   // wave-uniform base + lane*16B
}

#define MFMA_BF16(A_,B_,C_) __builtin_amdgcn_mfma_f32_16x16x32_bf16(A_,B_,C_,0,0,0)

// ---- ring-3 (72 KB), per-wave 64x64 — R9/R12 proven ----
__device__ __forceinline__ void gemm_main(const bf16* __restrict__ Ag,
                                          const bf16* __restrict__ Bg,
                                          int K, size_t bm, size_t bn,
                                          short* lds, f32x4 (&acc)[4][4]){
    constexpr int TILE = 384*32;
    const int NT = K >> 5;
    const int lane = threadIdx.x & 63;
    const int wid = threadIdx.x >> 6;
    const int wm = wid >> 1, wn = wid & 1;
    const int fr = lane & 15, g = lane >> 4;

    #pragma unroll
    for (int j = 0; j < 3; j++) stage_u(Ag, Bg, K, bm, bn, 0, lds, j);
    #pragma unroll
    for (int j = 0; j < 3; j++) stage_u(Ag, Bg, K, bm, bn, 1, lds + TILE, j);
    asm volatile("s_waitcnt vmcnt(3)" ::: "memory");
    __builtin_amdgcn_sched_barrier(0);
    __builtin_amdgcn_s_barrier();
    __builtin_amdgcn_sched_barrier(0);

    int cur = 0;
    for (int t = 0; t < NT; t++){
        short* buf = lds + cur*TILE;
        int sg = cur + 2; if (sg >= 3) sg -= 3;
        short* stg = lds + sg*TILE;
        short8 a[4], b[4];
        #pragma unroll
        for (int m = 0; m < 4; m++) a[m] = ld32(buf, wm*64 + m*16 + fr, g);
        #pragma unroll
        for (int n = 0; n < 4; n++) b[n] = ld32(buf, 256 + wn*64 + n*16 + fr, g);
        if (t + 2 < NT){
            stage_u(Ag, Bg, K, bm, bn, t+2, stg, 0);
            stage_u(Ag, Bg, K, bm, bn, t+2, stg, 1);
            stage_u(Ag, Bg, K, bm, bn, t+2, stg, 2);
        }
        __builtin_amdgcn_s_setprio(1);
        #pragma unroll
        for (int m = 0; m < 4; m++)
            #pragma unroll
            for (int n = 0; n < 4; n++)
                acc[m][n] = MFMA_BF16(a[m], b[n], acc[m][n]);
        __builtin_amdgcn_s_setprio(0);
        __builtin_amdgcn_sched_barrier(0);
        if (t + 2 < NT)      asm volatile("s_waitcnt vmcnt(3)" ::: "memory");
        else if (t + 1 < NT) asm volatile("s_waitcnt vmcnt(0)" ::: "memory");
        __builtin_amdgcn_sched_barrier(0);
        __builtin_amdgcn_s_barrier();
        __builtin_amdgcn_sched_barrier(0);
        cur = cur + 1 == 3 ? 0 : cur + 1;
    }
}

// ---------------- GEMM1: hn[8192x1024] x W_in[5376x1024]^T, segmented epilogue ----------------
// Grid 32m x 42n = 1344 blocks; group-major (GN=6) for L2-resident B-panel slices.
__global__ __launch_bounds__(512, 4) void k_gemm1_g(const bf16* __restrict__ A,
                                                    const bf16* __restrict__ B,
                                                    bf16* __restrict__ z,
                                                    bf16* __restrict__ xp,
                                                    bf16* __restrict__ Bc,
                                                    bf16* __restrict__ Cc,
                                                    float* __restrict__ dtr){
    extern __shared__ short lds[];
    int wg = (blockIdx.x & 7)*168 + (blockIdx.x >> 3);   // 1344 = 8*168, bijective
    int grp = wg / 192, rem = wg % 192;                  // 7 groups of 6 n-tiles
    int nt_ = grp*6 + rem % 6;
    int mt_ = rem / 6;
    size_t bm = (size_t)mt_ * 256;
    size_t bn = (size_t)nt_ * 128;
    f32x4 acc[4][4] = {};
    gemm_main(A, B, D_MODEL, bm, bn, lds, acc);
    const int lane = threadIdx.x & 63;
    const int wid = threadIdx.x >> 6;
    const int wm = wid >> 1, wn = wid & 1;
    int cr = (lane >> 4)*4, cc = lane & 15;
    #pragma unroll
    for (int m = 0; m < 4; m++){
        size_t r0 = bm + wm*64 + m*16 + cr;
        #pragma unroll
        for (int n = 0; n < 4; n++){
            int c = (int)bn + wn*64 + n*16 + cc;
            #pragma unroll
            for (int j = 0; j < 4; j++){
                float v = acc[m][n][j];
                size_t r = r0 + j;
                if (c < O1)            z  [r * D_INNER + c]        = f2b(v);
                else if (c < O2)       xp [r * D_INNER + (c - O1)] = f2b(v);
                else if (c < O3)       Bc [r * 512 + (c - O2)]     = f2b(v);
                else if (c < O4)       Cc [r * 512 + (c - O3)]     = f2b(v);
                else if (c < PROJ_N)   dtr[r * 8 + (c - O4)]       = v;
            }
        }
    }
}

// ---------------- GEMM2: yn[8192x2048] x (W_out*g_out)[1024x2048]^T + hidden -> f32 ----------------
// R12 config: 256x128 tile, grid 256, ring-3 72KB.
__global__ __launch_bounds__(512, 4) void k_gemm2_g(const bf16* __restrict__ A,
                                                    const bf16* __restrict__ B,
                                                    const float* __restrict__ res,
                                                    float* __restrict__ C){
    extern __shared__ short lds[];
    int wg = (blockIdx.x & 7)*32 + (blockIdx.x >> 3);    // 256 = 8*32, bijective
    size_t bm = (size_t)(wg >> 3) * 256;                 // 32 m-tiles
    size_t bn = (size_t)(wg & 7) * 128;                  // 8 n-tiles
    f32x4 acc[4][4] = {};
    gemm_main(A, B, D_INNER, bm, bn, lds, acc);
    const int lane = threadIdx.x & 63;
    const int wid = threadIdx.x >> 6;
    const int wm = wid >> 1, wn = wid & 1;
    int cr = (lane >> 4)*4, cc = lane & 15;
    #pragma unroll
    for (int m = 0; m < 4; m++){
        size_t r0 = bm + wm*64 + m*16 + cr;
        #pragma unroll
        for (int n = 0; n < 4; n++){
            size_t c = bn + wn*64 + n*16 + cc;
            #pragma unroll
            for (int j = 0; j < 4; j++){
                size_t r = r0 + j;
                C[r * D_MODEL + c] = acc[m][n][j] + res[r * D_MODEL + c];
            }
        }
    }
}

// ---------------- depthwise causal conv(4) + SiLU, s-parallel ----------------
__global__ __launch_bounds__(256) void k_conv_silu(const bf16* __restrict__ xp,
                                                   const float* __restrict__ cw,
                                                   const float* __restrict__ cb,
                                                   bf16* __restrict__ xout){
    int b = blockIdx.x;
    int c = blockIdx.y * 256 + threadIdx.x;
    int s0 = blockIdx.z * 32;
    float w0 = cw[c*4+0], w1 = cw[c*4+1], w2 = cw[c*4+2], w3 = cw[c*4+3];
    float bias = cb[c];
    const bf16* ib = xp + (size_t)b * SEQ * D_INNER + c;
    bf16* ob = xout + (size_t)b * SEQ * D_INNER + c;
    float x0 = 0.f, x1 = 0.f, x2 = 0.f;
    if (s0 >= 3){
        x0 = b2f(ib[(size_t)(s0-3) * D_INNER]);
        x1 = b2f(ib[(size_t)(s0-2) * D_INNER]);
        x2 = b2f(ib[(size_t)(s0-1) * D_INNER]);
    }
    #pragma unroll 4
    for (int s = s0; s < s0 + 32; s++){
        float x3 = b2f(ib[(size_t)s * D_INNER]);
        float a = x0*w0 + x1*w1 + x2*w2 + x3*w3 + bias;
        ob[(size_t)s * D_INNER] = f2b(silu_f(a));
        x0 = x1; x1 = x2; x2 = x3;
    }
}

// ---------------- dt_h -> logA cumsum (lcs) + tdec (prep folded in) ----------------
__global__ __launch_bounds__(64) void k_dt_lcs(const float* __restrict__ dtr,
                                               const float* __restrict__ W_dt,
                                               const float* __restrict__ b_dt,
                                               const float* __restrict__ A_log,
                                               float* __restrict__ lcs,
                                               float* __restrict__ tdec){
    __shared__ float sm[80];
    __shared__ float la[CHUNK][N_HEADS];
    int bc = blockIdx.x;
    int l = threadIdx.x;
    {
        int h = l >> 3, k = l & 7;
        float s = 0.f;
        for (int d = 0; d < HEAD_DIM; d++) s += W_dt[(size_t)(h*HEAD_DIM + d) * N_HEADS + k];
        sm[l] = s * (1.0f/(float)HEAD_DIM);
        if (l < 8){
            float sb = 0.f;
            for (int d = 0; d < HEAD_DIM; d++) sb += b_dt[l*HEAD_DIM + d];
            sm[64 + l] = sb * (1.0f/(float)HEAD_DIM);
            sm[72 + l] = -expf(A_log[l]);
        }
    }
    __syncthreads();
    const float* dr = dtr + (size_t)(bc*CHUNK + l) * 8;
    float d0 = dr[0], d1 = dr[1], d2 = dr[2], d3 = dr[3];
    float d4 = dr[4], d5 = dr[5], d6 = dr[6], d7 = dr[7];
    #pragma unroll
    for (int h = 0; h < 8; h++){
        float dt = sm[64+h]
                 + d0*sm[h*8+0] + d1*sm[h*8+1] + d2*sm[h*8+2] + d3*sm[h*8+3]
                 + d4*sm[h*8+4] + d5*sm[h*8+5] + d6*sm[h*8+6] + d7*sm[h*8+7];
        float sp = (dt > 20.f) ? dt : log1pf(expf(dt));
        la[l][h] = sp * sm[72+h];
    }
    __syncthreads();
    float out[8];
    #pragma unroll
    for (int h = 0; h < 8; h++) out[h] = 0.f;
    for (int l2 = 0; l2 <= l; l2++){
        #pragma unroll
        for (int h = 0; h < 8; h++) out[h] += la[l2][h];
    }
    float* lo = lcs + (size_t)(bc*CHUNK + l) * N_HEADS;
    #pragma unroll
    for (int h = 0; h < 8; h++) lo[h] = out[h];
    if (l == 63){
        #pragma unroll
        for (int h = 0; h < 8; h++) tdec[bc*N_HEADS + h] = expf(out[h]);
    }
}

// ================= fused chunked SSM (round-4/R12, verified) =================
#define LB   0
#define LC   4096
#define LGM  8192
#define LXT  12800
#define LSH  29184
#define LF   45568
#define LDS_BYTES 91904

__device__ __forceinline__ short8 frag_sw(const short* arr, int r, int k){
    return *(const short8*)(arr + r*64 + (k ^ ((r&7)<<3)));
}

__global__ __launch_bounds__(256, 1) void k_ssm(const bf16* __restrict__ Bc,
                                                const bf16* __restrict__ Cc,
                                                bf16* xg,
                                                const float* __restrict__ lcs,
                                                const float* __restrict__ tdec,
                                                const float* __restrict__ Dv){
    extern __shared__ short lds[];
    short* Blds  = lds + LB;
    short* Clds  = lds + LC;
    short* GMlds = lds + LGM;
    short* XTlds = lds + LXT;
    short* Shr   = lds + LSH;
    float* el = (float*)(lds + LF);
    float* ml = el + 64;
    float* ee = el + 128;

    const int tid = threadIdx.x;
    const int lane = tid & 63;
    const int wid = tid >> 6;
    const int fr = lane & 15;
    const int fk = (lane >> 4) * 8;
    const int r0 = (lane >> 4) * 4;
    const int b = blockIdx.x >> 3, h = blockIdx.x & 7;
    const float Dh = Dv[h];

    f32x4 carry[4][4] = {};

    for (int c = 0; c < NCHUNK; c++){
        const int bc = b*NCHUNK + c;
        __syncthreads();
        #pragma unroll
        for (int i = 0; i < 2; i++){
            int slot = i*256 + tid;
            int s = slot >> 3, u = slot & 7;
            size_t rb = (size_t)(bc*CHUNK + s) * 512 + h*64 + ((u ^ (s&7)) * 8);
            gl16(Bc + rb, Blds + slot*8);
            gl16(Cc + rb, Clds + slot*8);
        }
        #pragma unroll
        for (int i = 0; i < 8; i++){
            int slot = i*256 + tid;
            int s = slot >> 5, ck = slot & 31;
            gl16(xg + (size_t)(bc*CHUNK + s) * D_INNER + h*HEAD_DIM + ck*8, Shr + slot*8);
        }
        if (tid < 64) el[tid] = lcs[(size_t)(bc*CHUNK + tid) * N_HEADS + h];
        __syncthreads();
        if (tid < 64){
            float e63 = el[63];
            ml[tid] = expf(e63 - el[tid]);
            ee[tid] = expf(el[tid]);
        }
        #pragma unroll
        for (int i = 0; i < 8; i++){
            short8 t8;
            #pragma unroll
            for (int j = 0; j < 8; j++) t8[j] = Shr[(i*8 + j)*HEAD_DIM + tid];
            *(short8*)(XTlds + tid*64 + ((i*8) ^ ((tid&7)<<3))) = t8;
        }
        __syncthreads();
        {
            f32x4 accg[4] = {};
            #pragma unroll
            for (int kk = 0; kk < 2; kk++){
                short8 a = frag_sw(Clds, wid*16 + fr, kk*32 + fk);
                #pragma unroll
                for (int nt = 0; nt < 4; nt++){
                    short8 bb = frag_sw(Blds, nt*16 + fr, kk*32 + fk);
                    accg[nt] = __builtin_amdgcn_mfma_f32_16x16x32_bf16(a, bb, accg[nt], 0, 0, 0);
                }
            }
            #pragma unroll
            for (int nt = 0; nt < 4; nt++){
                int s = nt*16 + fr;
                float els = el[s];
                #pragma unroll
                for (int j = 0; j < 4; j++){
                    int l = wid*16 + r0 + j;
                    float f = (s <= l) ? expf(el[l] - els) : 0.f;
                    GMlds[l*72 + s] = f2s(accg[nt][j] * f);
                }
            }
            int crow = wid*16 + (lane >> 2), cq = lane & 3;
            float fe = ee[crow];
            #pragma unroll
            for (int half = 0; half < 2; half++){
                short8 v = *(short8*)(Clds + crow*64 + cq*16 + half*8);
                #pragma unroll
                for (int j = 0; j < 8; j++) v[j] = f2s(s2f(v[j]) * fe);
                *(short8*)(Clds + crow*64 + cq*16 + half*8) = v;
            }
        }
        #pragma unroll
        for (int mt = 0; mt < 4; mt++)
            #pragma unroll
            for (int nt = 0; nt < 4; nt++)
                #pragma unroll
                for (int j = 0; j < 4; j++){
                    int d = wid*64 + mt*16 + r0 + j;
                    int n = nt*16 + fr;
                    Shr[d*64 + (n ^ ((d&7)<<3))] = f2s(carry[mt][nt][j]);
                }
        float btv[16];
        {
            int bn_ = tid & 63, bq = tid >> 6;
            #pragma unroll
            for (int i = 0; i < 16; i++){
                int s = bq*16 + i;
                btv[i] = s2f(Blds[s*64 + (bn_ ^ ((s&7)<<3))]) * ml[s];
            }
        }
        __syncthreads();
        {
            int bn_ = tid & 63, bq = tid >> 6;
            #pragma unroll
            for (int i = 0; i < 16; i++){
                int s = bq*16 + i;
                Blds[bn_*64 + (s ^ ((bn_&7)<<3))] = f2s(btv[i]);
            }
        }
        {
            f32x4 accy[4][4] = {};
            #pragma unroll
            for (int kk = 0; kk < 2; kk++){
                short8 ag[4], ae[4], bx[4], bh[4];
                #pragma unroll
                for (int mt = 0; mt < 4; mt++){
                    ag[mt] = *(const short8*)(GMlds + (mt*16 + fr)*72 + kk*32 + fk);
                    ae[mt] = frag_sw(Clds, mt*16 + fr, kk*32 + fk);
                }
                #pragma unroll
                for (int nt = 0; nt < 4; nt++){
                    int d = wid*64 + nt*16 + fr;
                    bx[nt] = frag_sw(XTlds, d, kk*32 + fk);
                    bh[nt] = frag_sw(Shr,  d, kk*32 + fk);
                }
                #pragma unroll
                for (int mt = 0; mt < 4; mt++)
                    #pragma unroll
                    for (int nt = 0; nt < 4; nt++){
                        accy[mt][nt] = __builtin_amdgcn_mfma_f32_16x16x32_bf16(ag[mt], bx[nt], accy[mt][nt], 0, 0, 0);
                        accy[mt][nt] = __builtin_amdgcn_mfma_f32_16x16x32_bf16(ae[mt], bh[nt], accy[mt][nt], 0, 0, 0);
                    }
            }
            #pragma unroll
            for (int mt = 0; mt < 4; mt++)
                #pragma unroll
                for (int nt = 0; nt < 4; nt++){
                    int d = wid*64 + nt*16 + fr;
                    #pragma unroll
                    for (int j = 0; j < 4; j++){
                        int l = mt*16 + r0 + j;
                        float xv = s2f(XTlds[d*64 + (l ^ ((d&7)<<3))]);
                        xg[(size_t)(bc*CHUNK + l) * D_INNER + h*HEAD_DIM + d] = f2b(accy[mt][nt][j] + xv*Dh);
                    }
                }
        }
        __syncthreads();
        {
            f32x4 accs[4][4] = {};
            #pragma unroll
            for (int kk = 0; kk < 2; kk++){
                short8 ax[4], bt[4];
                #pragma unroll
                for (int mt = 0; mt < 4; mt++)
                    ax[mt] = frag_sw(XTlds, wid*64 + mt*16 + fr, kk*32 + fk);
                #pragma unroll
                for (int nt = 0; nt < 4; nt++)
                    bt[nt] = frag_sw(Blds, nt*16 + fr, kk*32 + fk);
                #pragma unroll
                for (int mt = 0; mt < 4; mt++)
                    #pragma unroll
                    for (int nt = 0; nt < 4; nt++)
                        accs[mt][nt] = __builtin_amdgcn_mfma_f32_16x16x32_bf16(ax[mt], bt[nt], accs[mt][nt], 0, 0, 0);
            }
            float td = tdec[bc*N_HEADS + h];
            #pragma unroll
            for (int mt = 0; mt < 4; mt++)
                #pragma unroll
                for (int nt = 0; nt < 4; nt++)
                    carry[mt][nt] = td * carry[mt][nt] + accs[mt][nt];
        }
    }
}

// ---------------- gate with silu(z) + RMSNorm (g_out folded into Wb2) -> yn bf16 ----------------
__global__ __launch_bounds__(256) void k_gate_rms(const bf16* __restrict__ y,
                                                  const bf16* __restrict__ z,
                                                  bf16* __restrict__ yn){
    int row = blockIdx.x, t = threadIdx.x;
    union { uint4 u; bf16 b[8]; } yv, zv, ov;
    yv.u = ((const uint4*)(y + (size_t)row * D_INNER))[t];
    zv.u = ((const uint4*)(z + (size_t)row * D_INNER))[t];
    float v[8];
    float ss = 0.f;
    #pragma unroll
    for (int i = 0; i < 8; i++){
        float a = b2f(yv.b[i]);
        float q = b2f(zv.b[i]);
        v[i] = a * silu_f(q);
        ss += v[i]*v[i];
    }
    ss = block_sum_256(ss);
    float sc = rsqrtf(ss * (1.0f/(float)D_INNER) + EPSF);
    #pragma unroll
    for (int i = 0; i < 8; i++) ov.b[i] = f2b(v[i]*sc);
    ((uint4*)(yn + (size_t)row * D_INNER))[t] = ov.u;
}

extern "C" void kernel_launch(void* const* d_in, const int* in_sizes, int n_in,
                              void* d_out, int out_size, void* d_ws, size_t ws_size,
                              hipStream_t stream){
    const float* hidden = (const float*)d_in[0];
    const float* W_in   = (const float*)d_in[1];
    const float* conv_w = (const float*)d_in[2];
    const float* conv_b = (const float*)d_in[3];
    const float* W_dt   = (const float*)d_in[4];
    const float* b_dt   = (const float*)d_in[5];
    const float* A_log  = (const float*)d_in[6];
    const float* Dv     = (const float*)d_in[7];
    const float* W_out  = (const float*)d_in[8];
    const float* g_in   = (const float*)d_in[9];
    const float* g_out  = (const float*)d_in[10];

    // workspace layout (bytes) — total ~150.0 MiB
    char* ws = (char*)d_ws;
    bf16*  z    = (bf16*)(ws + 0);            // 33,554,432
    bf16*  xp   = (bf16*)(ws + 33554432);     // 33,554,432 (pre-conv x; reused as yn)
    bf16*  x    = (bf16*)(ws + 67108864);     // 33,554,432 (conv out; ssm writes y in place)
    bf16*  Bc   = (bf16*)(ws + 100663296);    //  8,388,608
    bf16*  Cc   = (bf16*)(ws + 109051904);    //  8,388,608
    float* dtr  = (float*)(ws + 117440512);   //    262,144
    float* lcs  = (float*)(ws + 117702656);   //    262,144
    float* tdec = (float*)(ws + 117964800);   //      4,096
    bf16*  Wb1  = (bf16*)(ws + 117969408);    // 11,010,048
    bf16*  hnb  = (bf16*)(ws + 128979456);    // 16,777,216
    bf16*  Wb2  = (bf16*)(ws + 145756672);    //  4,194,304
    bf16*  yn   = xp;                          // xp dead after conv

    k_rms_in<<<ROWS, 256, 0, stream>>>(hidden, g_in, hnb);
    k_cvt_both<<<(N1 + D_MODEL*D_INNER)/1024, 256, 0, stream>>>(W_in, W_out, g_out, Wb1, Wb2);
    hipFuncSetAttribute((const void*)k_gemm1_g, hipFuncAttributeMaxDynamicSharedMemorySize, 73728);
    k_gemm1_g<<<(ROWS/256)*(PROJ_NPAD/128), 512, 73728, stream>>>(hnb, Wb1, z, xp, Bc, Cc, dtr);
    k_conv_silu<<<dim3(BATCH, D_INNER/256, SEQ/32), 256, 0, stream>>>(xp, conv_w, conv_b, x);
    k_dt_lcs<<<BATCH*NCHUNK, 64, 0, stream>>>(dtr, W_dt, b_dt, A_log, lcs, tdec);
    hipFuncSetAttribute((const void*)k_ssm, hipFuncAttributeMaxDynamicSharedMemorySize, LDS_BYTES);
    k_ssm<<<BATCH*N_HEADS, 256, LDS_BYTES, stream>>>(Bc, Cc, x, lcs, tdec, Dv);
    k_gate_rms<<<ROWS, 256, 0, stream>>>(x, z, yn);
    hipFuncSetAttribute((const void*)k_gemm2_g, hipFuncAttributeMaxDynamicSharedMemorySize, 73728);
    k_gemm2_g<<<(ROWS/256)*(D_MODEL/128), 512, 73728, stream>>>(yn, Wb2, hidden, (float*)d_out);
}